// Round 1
// baseline (358.429 us; speedup 1.0000x reference)
//
#include <hip/hip_runtime.h>
#include <math.h>

#define F 128
#define TWO_F 256
#define BN_EPS 1e-5f
#define PAD_A 136    // 128+8 bf16 row stride (gemm1 tile)
#define PAD_ACC 132  // fp32 accumulator row stride (32x132 = 16.9 KB)

typedef unsigned short ushort_t;
typedef unsigned char uchar_t;
typedef __attribute__((ext_vector_type(8))) short bfrag;   // 8 bf16
typedef __attribute__((ext_vector_type(4))) float ffrag;   // 4 fp32
typedef __attribute__((ext_vector_type(2))) float floatx2;

__device__ __forceinline__ float gelu_exact(float x) {
    return 0.5f * x * (1.0f + erff(x * 0.70710678118654752f));
}
__device__ __forceinline__ ushort_t f2bf(float x) {
    unsigned int u = __float_as_uint(x);
    u = (u + 0x7FFFu + ((u >> 16) & 1u)) >> 16;
    return (ushort_t)u;
}
__device__ __forceinline__ unsigned int pk2(float a, float b) {
    return (unsigned int)f2bf(a) | ((unsigned int)f2bf(b) << 16);
}

// ---------------- prep: param fold (blocks 0..128) + degree histogram (blocks 129+) ----------------
__global__ __launch_bounds__(256) void prep(
    const float* __restrict__ pre_w, const float* __restrict__ pre_b,
    const float* __restrict__ g1, const float* __restrict__ be1,
    const float* __restrict__ m1, const float* __restrict__ v1,
    const float* __restrict__ upd_w, const float* __restrict__ upd_b,
    const float* __restrict__ g2, const float* __restrict__ be2,
    const float* __restrict__ m2, const float* __restrict__ v2,
    ushort_t* __restrict__ W1T, ushort_t* __restrict__ W2T,
    float* __restrict__ b1f, float* __restrict__ b2f,
    const int* __restrict__ edges, int* __restrict__ counts, int nEdges, int histBlocks) {
    const int t = threadIdx.x;
    if (blockIdx.x == 0) {
        __shared__ float t1[F], t2[TWO_F];
        if (t < F) {
            float s = g1[t] * rsqrtf(v1[t] + BN_EPS);
            t1[t] = be1[t] - m1[t] * s;
        }
        {
            float s = g2[t] * rsqrtf(v2[t] + BN_EPS);
            t2[t] = be2[t] - m2[t] * s;
        }
        __syncthreads();
        if (t < F) {
            float acc = pre_b[t];
            #pragma unroll 4
            for (int k = 0; k < F; ++k) acc = fmaf(t1[k], pre_w[k * F + t], acc);
            b1f[t] = acc;
        } else {
            int j = t - F;
            float acc = upd_b[j];
            #pragma unroll 4
            for (int k = 0; k < TWO_F; ++k) acc = fmaf(t2[k], upd_w[k * F + j], acc);
            b2f[j] = acc;
        }
    } else if (blockIdx.x <= 128) {
        int idx = (blockIdx.x - 1) * 256 + t;
        if (idx < F * F) {
            int k = idx & (F - 1), n = idx >> 7;
            float s = g1[k] * rsqrtf(v1[k] + BN_EPS);
            W1T[idx] = f2bf(s * pre_w[k * F + n]);
        }
        {
            int k = idx & (TWO_F - 1), n = idx >> 8;
            float s = g2[k] * rsqrtf(v2[k] + BN_EPS);
            W2T[idx] = f2bf(s * upd_w[k * F + n]);
        }
    } else {
        int b = blockIdx.x - 129;
        for (int i = b * 256 + t; i < nEdges; i += histBlocks * 256)
            atomicAdd(&counts[edges[i]], 1);
    }
}

// ---------------- CSR scans ----------------
__global__ __launch_bounds__(1024) void scan_pass1(const int* __restrict__ counts,
                                                   int* __restrict__ offsets,
                                                   int* __restrict__ blocksums, int n) {
    __shared__ int sb[1024];
    const int t = threadIdx.x;
    int idx = blockIdx.x * 1024 + t;
    int v = (idx < n) ? counts[idx] : 0;
    sb[t] = v;
    __syncthreads();
    for (int off = 1; off < 1024; off <<= 1) {
        int x = (t >= off) ? sb[t - off] : 0;
        __syncthreads();
        sb[t] += x;
        __syncthreads();
    }
    if (idx < n) offsets[idx + 1] = sb[t];
    if (t == 1023) blocksums[blockIdx.x] = sb[t];
}

__global__ __launch_bounds__(1024) void scan_pass3(const int* __restrict__ counts,
                                                   int* __restrict__ offsets,
                                                   const int* __restrict__ blocksums,
                                                   int* __restrict__ cursor, int n) {
    __shared__ int sb[1024];
    const int t = threadIdx.x;
    sb[t] = (t < blockIdx.x) ? blocksums[t] : 0;
    __syncthreads();
    #pragma unroll
    for (int off = 512; off > 0; off >>= 1) {
        if (t < off) sb[t] += sb[t + off];
        __syncthreads();
    }
    int base = sb[0];
    int idx = blockIdx.x * 1024 + t;
    if (idx < n) {
        int incl = offsets[idx + 1] + base;
        offsets[idx + 1] = incl;
        cursor[idx] = incl - counts[idx];
    }
    if (blockIdx.x == 0 && t == 0) offsets[0] = 0;
}

// ---------------- gemm1 (blocks 0..gB-1) + fill_csr (blocks gB+) ----------------
// csr entry: x = src | (dstLocal<<27) where dstLocal = dst & 31 (node_fused blocks are 32-aligned)
__global__ __launch_bounds__(256) void gemm1_fill(
    const float* __restrict__ nodes, const ushort_t* __restrict__ W1T,
    const float* __restrict__ b1f, uchar_t* __restrict__ G8, int nNodes,
    const int* __restrict__ edges, const float* __restrict__ ew,
    int* __restrict__ cursor, int2* __restrict__ csr, int nEdges,
    int gB, int fillBlocks) {
    __shared__ ushort_t As[64 * PAD_A];
    __shared__ float bs[F];
    const int t = threadIdx.x;

    if (blockIdx.x >= gB) {   // fill_csr part
        int b = blockIdx.x - gB;
        for (int e = b * 256 + t; e < nEdges; e += fillBlocks * 256) {
            int dst = edges[e];
            int pos = atomicAdd(&cursor[dst], 1);
            int src = edges[nEdges + e];
            csr[pos] = make_int2(src | ((dst & 31) << 27), __float_as_int(ew[e]));
        }
        return;
    }

    const int base = blockIdx.x * 64;
    {
        int r = t >> 2, q = t & 3;
        int n = base + r;
        int sn = (n < nNodes) ? n : 0;
        const float4* src = reinterpret_cast<const float4*>(nodes + (size_t)sn * F + q * 32);
        uint4 pv[4];
        #pragma unroll
        for (int i = 0; i < 4; ++i) {
            float4 a = src[2 * i], b = src[2 * i + 1];
            pv[i].x = pk2(a.x, a.y); pv[i].y = pk2(a.z, a.w);
            pv[i].z = pk2(b.x, b.y); pv[i].w = pk2(b.z, b.w);
        }
        uint4* dst = reinterpret_cast<uint4*>(As + r * PAD_A + q * 32);
        #pragma unroll
        for (int i = 0; i < 4; ++i) dst[i] = pv[i];
    }
    if (t < F) bs[t] = b1f[t];
    __syncthreads();

    const int lane = t & 63, w = t >> 6;
    const int m = lane & 15, quad = lane >> 4;

    ffrag acc[8];
    #pragma unroll
    for (int c = 0; c < 8; ++c) acc[c] = (ffrag){0.f, 0.f, 0.f, 0.f};

    #pragma unroll
    for (int kk = 0; kk < 4; ++kk) {
        int k0 = kk * 32 + quad * 8;
        bfrag a = *reinterpret_cast<const bfrag*>(As + (w * 16 + m) * PAD_A + k0);
        #pragma unroll
        for (int c = 0; c < 8; ++c) {
            bfrag b = *reinterpret_cast<const bfrag*>(W1T + (size_t)(c * 16 + m) * F + k0);
            acc[c] = __builtin_amdgcn_mfma_f32_16x16x32_bf16(a, b, acc[c], 0, 0, 0);
        }
    }

    #pragma unroll
    for (int c = 0; c < 8; ++c) {
        int feat = c * 16 + m;
        float bj = bs[feat];
        #pragma unroll
        for (int i = 0; i < 4; ++i) {
            int n = base + w * 16 + quad * 4 + i;
            if (n < nNodes) {
                float v = gelu_exact(acc[c][i] + bj);
                int pkd = __builtin_amdgcn_cvt_pk_fp8_f32(v, v, 0, false);
                G8[(size_t)n * F + feat] = (uchar_t)(pkd & 0xFF);
            }
        }
    }
}

// ---------------- fused aggregation + FFN2: 32 nodes/block ----------------
// Gather is EDGE-balanced: block's CSR slice is contiguous (dst-sorted); each
// thread takes an equal contiguous run of edges (8 threads/edge, 16 fp8 feats),
// register-accumulates same-dst runs, flushes via ds_add_f32 into fp32 LDS acc.
// MFMA A-fragments: node half read directly from global fp32, agg half from LDS
// acc with 1/(deg*F) folded into the bf16 pack.
__global__ __launch_bounds__(256) void node_fused(
    const float* __restrict__ nodes, const uchar_t* __restrict__ G8,
    const int* __restrict__ offsets, const int2* __restrict__ csr,
    const ushort_t* __restrict__ W2T, const float* __restrict__ b2f,
    float* __restrict__ out, int nNodes) {
    __shared__ float accS[32 * PAD_ACC];   // 16.9 KB fp32 accumulator
    __shared__ float bs[F];
    __shared__ int offs[33];
    const int t = threadIdx.x;
    const int base = blockIdx.x * 32;

    if (t < F) bs[t] = b2f[t];
    if (t < 33) {
        int idx = base + t;
        offs[t] = offsets[(idx < nNodes) ? idx : nNodes];
    }
    for (int i = t; i < 32 * PAD_ACC; i += 256) accS[i] = 0.f;
    __syncthreads();

    // ---- edge-balanced gather ----
    {
        const int eg = t >> 3, oct = t & 7;
        const int eBeg = offs[0], eEnd = offs[32];
        const int nE = eEnd - eBeg;
        const int len = (nE + 31) >> 5;
        int e = eBeg + eg * len;
        const int eStop = min(e + len, eEnd);

        float vacc[16];
        #pragma unroll
        for (int j = 0; j < 16; ++j) vacc[j] = 0.f;
        int curRl = -1;

        if (e < eStop) {
            int2 mc = csr[e];
            uint4 ac = *reinterpret_cast<const uint4*>(
                G8 + (size_t)(((unsigned int)mc.x) & 0x07FFFFFFu) * F + oct * 16);
            while (true) {
                bool more = (e + 1) < eStop;
                int2 mn;
                uint4 an;
                if (more) {   // 1-deep prefetch of next (csr, G8) pair
                    mn = csr[e + 1];
                    an = *reinterpret_cast<const uint4*>(
                        G8 + (size_t)(((unsigned int)mn.x) & 0x07FFFFFFu) * F + oct * 16);
                }
                int rl = (int)(((unsigned int)mc.x) >> 27);
                float w = __int_as_float(mc.y);
                if (rl != curRl) {
                    if (curRl >= 0) {
                        float* rowp = accS + curRl * PAD_ACC + oct * 16;
                        #pragma unroll
                        for (int j = 0; j < 16; ++j) atomicAdd(&rowp[j], vacc[j]);
                        #pragma unroll
                        for (int j = 0; j < 16; ++j) vacc[j] = 0.f;
                    }
                    curRl = rl;
                }
                floatx2 p;
                p = __builtin_amdgcn_cvt_pk_f32_fp8(ac.x, false); vacc[0]  = fmaf(w, p.x, vacc[0]);  vacc[1]  = fmaf(w, p.y, vacc[1]);
                p = __builtin_amdgcn_cvt_pk_f32_fp8(ac.x, true ); vacc[2]  = fmaf(w, p.x, vacc[2]);  vacc[3]  = fmaf(w, p.y, vacc[3]);
                p = __builtin_amdgcn_cvt_pk_f32_fp8(ac.y, false); vacc[4]  = fmaf(w, p.x, vacc[4]);  vacc[5]  = fmaf(w, p.y, vacc[5]);
                p = __builtin_amdgcn_cvt_pk_f32_fp8(ac.y, true ); vacc[6]  = fmaf(w, p.x, vacc[6]);  vacc[7]  = fmaf(w, p.y, vacc[7]);
                p = __builtin_amdgcn_cvt_pk_f32_fp8(ac.z, false); vacc[8]  = fmaf(w, p.x, vacc[8]);  vacc[9]  = fmaf(w, p.y, vacc[9]);
                p = __builtin_amdgcn_cvt_pk_f32_fp8(ac.z, true ); vacc[10] = fmaf(w, p.x, vacc[10]); vacc[11] = fmaf(w, p.y, vacc[11]);
                p = __builtin_amdgcn_cvt_pk_f32_fp8(ac.w, false); vacc[12] = fmaf(w, p.x, vacc[12]); vacc[13] = fmaf(w, p.y, vacc[13]);
                p = __builtin_amdgcn_cvt_pk_f32_fp8(ac.w, true ); vacc[14] = fmaf(w, p.x, vacc[14]); vacc[15] = fmaf(w, p.y, vacc[15]);
                if (!more) break;
                mc = mn; ac = an; ++e;
            }
            float* rowp = accS + curRl * PAD_ACC + oct * 16;
            #pragma unroll
            for (int j = 0; j < 16; ++j) atomicAdd(&rowp[j], vacc[j]);
        }
    }
    __syncthreads();

    // ---- MFMA: 4 waves = 2 row-groups x 2 col-groups; wave = 16 rows x 64 cols ----
    const int lane = t & 63, wv = t >> 6;
    const int m = lane & 15, quad = lane >> 4;
    const int rg = wv & 1, cg = wv >> 1;
    const int arow = rg * 16 + m;
    const int deg = offs[arow + 1] - offs[arow];
    const float inv = (deg > 0) ? 1.0f / ((float)deg * (float)F) : 0.f;  // counter = deg*F quirk

    const int grow = base + arow;
    const float4* nrow = reinterpret_cast<const float4*>(
        nodes + (size_t)((grow < nNodes) ? grow : 0) * F);
    const float4* arow4 = reinterpret_cast<const float4*>(accS + arow * PAD_ACC);

    ffrag acc[4];
    #pragma unroll
    for (int c = 0; c < 4; ++c) acc[c] = (ffrag){0.f, 0.f, 0.f, 0.f};

    // node half (k = 0..127), A direct from global fp32
    #pragma unroll
    for (int kk = 0; kk < 4; ++kk) {
        int c0 = kk * 32 + quad * 8;
        float4 f0 = nrow[kk * 8 + quad * 2];
        float4 f1 = nrow[kk * 8 + quad * 2 + 1];
        bfrag a;
        unsigned int* au = reinterpret_cast<unsigned int*>(&a);
        au[0] = pk2(f0.x, f0.y); au[1] = pk2(f0.z, f0.w);
        au[2] = pk2(f1.x, f1.y); au[3] = pk2(f1.z, f1.w);
        #pragma unroll
        for (int c = 0; c < 4; ++c) {
            int feat = cg * 64 + c * 16 + m;
            bfrag b = *reinterpret_cast<const bfrag*>(W2T + (size_t)feat * TWO_F + c0);
            acc[c] = __builtin_amdgcn_mfma_f32_16x16x32_bf16(a, b, acc[c], 0, 0, 0);
        }
    }
    // agg half (k = 128..255), A from LDS fp32 acc * inv
    #pragma unroll
    for (int kk = 0; kk < 4; ++kk) {
        int c0 = kk * 32 + quad * 8;
        float4 f0 = arow4[kk * 8 + quad * 2];
        float4 f1 = arow4[kk * 8 + quad * 2 + 1];
        bfrag a;
        unsigned int* au = reinterpret_cast<unsigned int*>(&a);
        au[0] = pk2(f0.x * inv, f0.y * inv); au[1] = pk2(f0.z * inv, f0.w * inv);
        au[2] = pk2(f1.x * inv, f1.y * inv); au[3] = pk2(f1.z * inv, f1.w * inv);
        #pragma unroll
        for (int c = 0; c < 4; ++c) {
            int feat = cg * 64 + c * 16 + m;
            bfrag b = *reinterpret_cast<const bfrag*>(W2T + (size_t)feat * TWO_F + 128 + c0);
            acc[c] = __builtin_amdgcn_mfma_f32_16x16x32_bf16(a, b, acc[c], 0, 0, 0);
        }
    }

    #pragma unroll
    for (int c = 0; c < 4; ++c) {
        int feat = cg * 64 + c * 16 + m;
        float bj = bs[feat];
        #pragma unroll
        for (int i = 0; i < 4; ++i) {
            int n = base + rg * 16 + quad * 4 + i;
            if (n < nNodes) out[(size_t)n * F + feat] = gelu_exact(acc[c][i] + bj);
        }
    }
}

extern "C" void kernel_launch(void* const* d_in, const int* in_sizes, int n_in,
                              void* d_out, int out_size, void* d_ws, size_t ws_size,
                              hipStream_t stream) {
    const float* nodes  = (const float*)d_in[0];
    const int*   edges  = (const int*)d_in[1];
    const float* ew     = (const float*)d_in[2];
    const float* pre_g  = (const float*)d_in[3];
    const float* pre_be = (const float*)d_in[4];
    const float* pre_m  = (const float*)d_in[5];
    const float* pre_v  = (const float*)d_in[6];
    const float* pre_w  = (const float*)d_in[7];
    const float* pre_b  = (const float*)d_in[8];
    const float* upd_g  = (const float*)d_in[9];
    const float* upd_be = (const float*)d_in[10];
    const float* upd_m  = (const float*)d_in[11];
    const float* upd_v  = (const float*)d_in[12];
    const float* upd_w  = (const float*)d_in[13];
    const float* upd_b  = (const float*)d_in[14];
    float* out = (float*)d_out;

    const int nNodes = in_sizes[0] / F;
    const int nEdges = in_sizes[2];
    const int nChunks = (nNodes + 1023) / 1024;
    const int histBlocks = 1024;
    const int gB = (nNodes + 63) / 64;
    const int fillBlocks = 1024;

    // ws layout (16B aligned blocks)
    char* p = (char*)d_ws;
    int*      counts    = (int*)p;       p += (size_t)nNodes * 4;
    int*      offsets   = (int*)p;       p += (size_t)(nNodes + 4) * 4;
    int*      cursor    = (int*)p;       p += (size_t)nNodes * 4;
    int*      blocksums = (int*)p;       p += 1024 * 4;
    int2*     csr       = (int2*)p;      p += (size_t)nEdges * 8;
    float*    b1f       = (float*)p;     p += F * 4;
    float*    b2f       = (float*)p;     p += F * 4;
    ushort_t* W1T       = (ushort_t*)p;  p += F * F * 2;
    ushort_t* W2T       = (ushort_t*)p;  p += TWO_F * F * 2;
    uchar_t*  G8        = (uchar_t*)p;

    hipMemsetAsync(counts, 0, (size_t)nNodes * 4, stream);

    prep<<<129 + histBlocks, 256, 0, stream>>>(
        pre_w, pre_b, pre_g, pre_be, pre_m, pre_v,
        upd_w, upd_b, upd_g, upd_be, upd_m, upd_v,
        W1T, W2T, b1f, b2f, edges, counts, nEdges, histBlocks);

    scan_pass1<<<nChunks, 1024, 0, stream>>>(counts, offsets, blocksums, nNodes);
    scan_pass3<<<nChunks, 1024, 0, stream>>>(counts, offsets, blocksums, cursor, nNodes);

    gemm1_fill<<<gB + fillBlocks, 256, 0, stream>>>(
        nodes, W1T, b1f, G8, nNodes, edges, ew, cursor, csr, nEdges, gB, fillBlocks);

    node_fused<<<(nNodes + 31) / 32, 256, 0, stream>>>(
        nodes, G8, offsets, csr, W2T, b2f, out, nNodes);
}

// Round 2
// 300.964 us; speedup vs baseline: 1.1909x; 1.1909x over previous
//
#include <hip/hip_runtime.h>
#include <math.h>

#define F 128
#define TWO_F 256
#define BN_EPS 1e-5f
#define PAD_A 136    // 128+8 bf16 row stride (gemm1 tile)
#define PAD_A2 264   // 256+8 bf16 row stride (node_fused tile)
#define CSR_S 512    // per-block CSR LDS stage capacity (mean ~192, 23 sigma headroom)

typedef unsigned short ushort_t;
typedef unsigned char uchar_t;
typedef __attribute__((ext_vector_type(8))) short bfrag;   // 8 bf16
typedef __attribute__((ext_vector_type(4))) float ffrag;   // 4 fp32
typedef __attribute__((ext_vector_type(2))) float floatx2;

__device__ __forceinline__ float gelu_exact(float x) {
    return 0.5f * x * (1.0f + erff(x * 0.70710678118654752f));
}
__device__ __forceinline__ ushort_t f2bf(float x) {
    unsigned int u = __float_as_uint(x);
    u = (u + 0x7FFFu + ((u >> 16) & 1u)) >> 16;
    return (ushort_t)u;
}
__device__ __forceinline__ unsigned int pk2(float a, float b) {
    return (unsigned int)f2bf(a) | ((unsigned int)f2bf(b) << 16);
}

__device__ __forceinline__ void fma4_fp8(float* acc, unsigned int d, float w) {
    floatx2 lo = __builtin_amdgcn_cvt_pk_f32_fp8(d, false);
    floatx2 hi = __builtin_amdgcn_cvt_pk_f32_fp8(d, true);
    acc[0] = fmaf(w, lo.x, acc[0]);
    acc[1] = fmaf(w, lo.y, acc[1]);
    acc[2] = fmaf(w, hi.x, acc[2]);
    acc[3] = fmaf(w, hi.y, acc[3]);
}
__device__ __forceinline__ void fma16_fp8(float* acc, uint4 a, float w) {
    fma4_fp8(acc + 0,  a.x, w); fma4_fp8(acc + 4,  a.y, w);
    fma4_fp8(acc + 8,  a.z, w); fma4_fp8(acc + 12, a.w, w);
}

// 8-deep batched gather: addresses come from LDS-staged csr (OVF=false) so all
// G8 loads in a batch are independent and issue back-to-back.
template<bool OVF>
__device__ __forceinline__ void gather_edges(
    float* acc, const uchar_t* __restrict__ G8, const int2* __restrict__ csr_s,
    const int2* __restrict__ csr_g, int eBeg, int sIdx, int eIdx, int q) {
    int i = sIdx;
    while (i < eIdx) {
        int c = eIdx - i;
        c = (c > 8) ? 8 : c;
        uint4 av[8];
        float wv[8];
        #pragma unroll
        for (int j = 0; j < 8; ++j) {
            if (j < c) {
                int2 m = OVF ? csr_g[eBeg + i + j] : csr_s[i + j];
                wv[j] = __int_as_float(m.y);
                av[j] = *reinterpret_cast<const uint4*>(
                    G8 + (size_t)(unsigned int)m.x * F + q * 16);
            }
        }
        #pragma unroll
        for (int j = 0; j < 8; ++j)
            if (j < c) fma16_fp8(acc, av[j], wv[j]);
        i += c;
    }
}

// ---------------- prep: param fold (blocks 0..128) + degree histogram (blocks 129+) ----------------
__global__ __launch_bounds__(256) void prep(
    const float* __restrict__ pre_w, const float* __restrict__ pre_b,
    const float* __restrict__ g1, const float* __restrict__ be1,
    const float* __restrict__ m1, const float* __restrict__ v1,
    const float* __restrict__ upd_w, const float* __restrict__ upd_b,
    const float* __restrict__ g2, const float* __restrict__ be2,
    const float* __restrict__ m2, const float* __restrict__ v2,
    ushort_t* __restrict__ W1T, ushort_t* __restrict__ W2T,
    float* __restrict__ b1f, float* __restrict__ b2f,
    const int* __restrict__ edges, int* __restrict__ counts, int nEdges, int histBlocks) {
    const int t = threadIdx.x;
    if (blockIdx.x == 0) {
        __shared__ float t1[F], t2[TWO_F];
        if (t < F) {
            float s = g1[t] * rsqrtf(v1[t] + BN_EPS);
            t1[t] = be1[t] - m1[t] * s;
        }
        {
            float s = g2[t] * rsqrtf(v2[t] + BN_EPS);
            t2[t] = be2[t] - m2[t] * s;
        }
        __syncthreads();
        if (t < F) {
            float acc = pre_b[t];
            #pragma unroll 4
            for (int k = 0; k < F; ++k) acc = fmaf(t1[k], pre_w[k * F + t], acc);
            b1f[t] = acc;
        } else {
            int j = t - F;
            float acc = upd_b[j];
            #pragma unroll 4
            for (int k = 0; k < TWO_F; ++k) acc = fmaf(t2[k], upd_w[k * F + j], acc);
            b2f[j] = acc;
        }
    } else if (blockIdx.x <= 128) {
        int idx = (blockIdx.x - 1) * 256 + t;
        if (idx < F * F) {
            int k = idx & (F - 1), n = idx >> 7;
            float s = g1[k] * rsqrtf(v1[k] + BN_EPS);
            W1T[idx] = f2bf(s * pre_w[k * F + n]);
        }
        {
            int k = idx & (TWO_F - 1), n = idx >> 8;
            float s = g2[k] * rsqrtf(v2[k] + BN_EPS);
            W2T[idx] = f2bf(s * upd_w[k * F + n]);
        }
    } else {
        int b = blockIdx.x - 129;
        for (int i = b * 256 + t; i < nEdges; i += histBlocks * 256)
            atomicAdd(&counts[edges[i]], 1);
    }
}

// ---------------- CSR scans ----------------
__global__ __launch_bounds__(1024) void scan_pass1(const int* __restrict__ counts,
                                                   int* __restrict__ offsets,
                                                   int* __restrict__ blocksums, int n) {
    __shared__ int sb[1024];
    const int t = threadIdx.x;
    int idx = blockIdx.x * 1024 + t;
    int v = (idx < n) ? counts[idx] : 0;
    sb[t] = v;
    __syncthreads();
    for (int off = 1; off < 1024; off <<= 1) {
        int x = (t >= off) ? sb[t - off] : 0;
        __syncthreads();
        sb[t] += x;
        __syncthreads();
    }
    if (idx < n) offsets[idx + 1] = sb[t];
    if (t == 1023) blocksums[blockIdx.x] = sb[t];
}

__global__ __launch_bounds__(1024) void scan_pass3(const int* __restrict__ counts,
                                                   int* __restrict__ offsets,
                                                   const int* __restrict__ blocksums,
                                                   int* __restrict__ cursor, int n) {
    __shared__ int sb[1024];
    const int t = threadIdx.x;
    sb[t] = (t < blockIdx.x) ? blocksums[t] : 0;
    __syncthreads();
    #pragma unroll
    for (int off = 512; off > 0; off >>= 1) {
        if (t < off) sb[t] += sb[t + off];
        __syncthreads();
    }
    int base = sb[0];
    int idx = blockIdx.x * 1024 + t;
    if (idx < n) {
        int incl = offsets[idx + 1] + base;
        offsets[idx + 1] = incl;
        cursor[idx] = incl - counts[idx];
    }
    if (blockIdx.x == 0 && t == 0) offsets[0] = 0;
}

// ---------------- gemm1 (blocks 0..gB-1) + fill_csr (blocks gB+) ----------------
__global__ __launch_bounds__(256) void gemm1_fill(
    const float* __restrict__ nodes, const ushort_t* __restrict__ W1T,
    const float* __restrict__ b1f, uchar_t* __restrict__ G8, int nNodes,
    const int* __restrict__ edges, const float* __restrict__ ew,
    int* __restrict__ cursor, int2* __restrict__ csr, int nEdges,
    int gB, int fillBlocks) {
    __shared__ ushort_t As[64 * PAD_A];
    __shared__ float bs[F];
    const int t = threadIdx.x;

    if (blockIdx.x >= gB) {   // fill_csr part
        int b = blockIdx.x - gB;
        for (int e = b * 256 + t; e < nEdges; e += fillBlocks * 256) {
            int dst = edges[e];
            int pos = atomicAdd(&cursor[dst], 1);
            csr[pos] = make_int2(edges[nEdges + e], __float_as_int(ew[e]));
        }
        return;
    }

    const int base = blockIdx.x * 64;
    {
        int r = t >> 2, q = t & 3;
        int n = base + r;
        int sn = (n < nNodes) ? n : 0;
        const float4* src = reinterpret_cast<const float4*>(nodes + (size_t)sn * F + q * 32);
        uint4 pv[4];
        #pragma unroll
        for (int i = 0; i < 4; ++i) {
            float4 a = src[2 * i], b = src[2 * i + 1];
            pv[i].x = pk2(a.x, a.y); pv[i].y = pk2(a.z, a.w);
            pv[i].z = pk2(b.x, b.y); pv[i].w = pk2(b.z, b.w);
        }
        uint4* dst = reinterpret_cast<uint4*>(As + r * PAD_A + q * 32);
        #pragma unroll
        for (int i = 0; i < 4; ++i) dst[i] = pv[i];
    }
    if (t < F) bs[t] = b1f[t];
    __syncthreads();

    const int lane = t & 63, w = t >> 6;
    const int m = lane & 15, quad = lane >> 4;

    ffrag acc[8];
    #pragma unroll
    for (int c = 0; c < 8; ++c) acc[c] = (ffrag){0.f, 0.f, 0.f, 0.f};

    #pragma unroll
    for (int kk = 0; kk < 4; ++kk) {
        int k0 = kk * 32 + quad * 8;
        bfrag a = *reinterpret_cast<const bfrag*>(As + (w * 16 + m) * PAD_A + k0);
        #pragma unroll
        for (int c = 0; c < 8; ++c) {
            bfrag b = *reinterpret_cast<const bfrag*>(W1T + (size_t)(c * 16 + m) * F + k0);
            acc[c] = __builtin_amdgcn_mfma_f32_16x16x32_bf16(a, b, acc[c], 0, 0, 0);
        }
    }

    #pragma unroll
    for (int c = 0; c < 8; ++c) {
        int feat = c * 16 + m;
        float bj = bs[feat];
        #pragma unroll
        for (int i = 0; i < 4; ++i) {
            int n = base + w * 16 + quad * 4 + i;
            if (n < nNodes) {
                float v = gelu_exact(acc[c][i] + bj);
                int pkd = __builtin_amdgcn_cvt_pk_fp8_f32(v, v, 0, false);
                G8[(size_t)n * F + feat] = (uchar_t)(pkd & 0xFF);
            }
        }
    }
}

// ---------------- fused aggregation + FFN2: 32 nodes/block, 8 threads/node ----------------
// Round-0 structure + two latency fixes:
//   (1) block's contiguous CSR slice staged into LDS -> G8 addresses at LDS latency
//   (2) 8-deep batched independent G8 loads per thread
__global__ __launch_bounds__(256) void node_fused(
    const float* __restrict__ nodes, const uchar_t* __restrict__ G8,
    const int* __restrict__ offsets, const int2* __restrict__ csr,
    const ushort_t* __restrict__ W2T, const float* __restrict__ b2f,
    float* __restrict__ out, int nNodes) {
    __shared__ ushort_t As[32 * PAD_A2];   // ~16.9 KB
    __shared__ float bs[F];
    __shared__ int offs[33];
    __shared__ int2 csr_s[CSR_S];          // 4 KB
    const int t = threadIdx.x;
    const int base = blockIdx.x * 32;
    const int r = t >> 3, q = t & 7;       // r: node slot 0..31, q: feat octant (16 feats)

    if (t < F) bs[t] = b2f[t];
    if (t < 33) {
        int idx = base + t;
        offs[t] = offsets[(idx < nNodes) ? idx : nNodes];
    }
    __syncthreads();

    const int eBeg = offs[0];
    const int nE = offs[32] - eBeg;
    const int nEc = (nE < CSR_S) ? nE : CSR_S;

    // cooperative CSR stage (coalesced int2)
    for (int i = t; i < nEc; i += 256) csr_s[i] = csr[eBeg + i];

    // stage fp32 node row half (16 feats/thread -> bf16)
    {
        int n = base + r;
        int sn = (n < nNodes) ? n : 0;
        const float4* src = reinterpret_cast<const float4*>(nodes + (size_t)sn * F + q * 16);
        uint4 pv[2];
        #pragma unroll
        for (int i = 0; i < 2; ++i) {
            float4 a = src[2 * i], b = src[2 * i + 1];
            pv[i].x = pk2(a.x, a.y); pv[i].y = pk2(a.z, a.w);
            pv[i].z = pk2(b.x, b.y); pv[i].w = pk2(b.z, b.w);
        }
        uint4* dst = reinterpret_cast<uint4*>(As + r * PAD_A2 + q * 16);
        dst[0] = pv[0]; dst[1] = pv[1];
    }
    __syncthreads();

    // gather: 8 threads/node, 16 fp8 feats each, 8-deep batched loads
    {
        float acc[16];
        #pragma unroll
        for (int j = 0; j < 16; ++j) acc[j] = 0.f;
        const int sIdx = offs[r] - eBeg;
        const int eIdx = offs[r + 1] - eBeg;
        if (eIdx <= nEc)
            gather_edges<false>(acc, G8, csr_s, csr, eBeg, sIdx, eIdx, q);
        else
            gather_edges<true>(acc, G8, csr_s, csr, eBeg, sIdx, eIdx, q);  // ~never
        int deg = eIdx - sIdx;
        float inv = (deg > 0) ? 1.0f / ((float)deg * (float)F) : 0.f;  // counter = deg*F quirk
        unsigned int* dstu = reinterpret_cast<unsigned int*>(As + r * PAD_A2 + F + q * 16);
        #pragma unroll
        for (int j = 0; j < 8; ++j) dstu[j] = pk2(acc[2 * j] * inv, acc[2 * j + 1] * inv);
    }
    __syncthreads();

    // MFMA: 4 waves = 2 row-groups x 2 col-groups; each wave 16 rows x 64 cols
    const int lane = t & 63, w = t >> 6;
    const int m = lane & 15, quad = lane >> 4;
    const int rg = w & 1, cg = w >> 1;

    ffrag acc[4];
    #pragma unroll
    for (int c = 0; c < 4; ++c) acc[c] = (ffrag){0.f, 0.f, 0.f, 0.f};

    #pragma unroll
    for (int kk = 0; kk < 8; ++kk) {
        int k0 = kk * 32 + quad * 8;
        bfrag a = *reinterpret_cast<const bfrag*>(As + (rg * 16 + m) * PAD_A2 + k0);
        #pragma unroll
        for (int c = 0; c < 4; ++c) {
            int feat = cg * 64 + c * 16 + m;
            bfrag b = *reinterpret_cast<const bfrag*>(W2T + (size_t)feat * TWO_F + k0);
            acc[c] = __builtin_amdgcn_mfma_f32_16x16x32_bf16(a, b, acc[c], 0, 0, 0);
        }
    }

    #pragma unroll
    for (int c = 0; c < 4; ++c) {
        int feat = cg * 64 + c * 16 + m;
        float bj = bs[feat];
        #pragma unroll
        for (int i = 0; i < 4; ++i) {
            int n = base + rg * 16 + quad * 4 + i;
            if (n < nNodes) out[(size_t)n * F + feat] = gelu_exact(acc[c][i] + bj);
        }
    }
}

extern "C" void kernel_launch(void* const* d_in, const int* in_sizes, int n_in,
                              void* d_out, int out_size, void* d_ws, size_t ws_size,
                              hipStream_t stream) {
    const float* nodes  = (const float*)d_in[0];
    const int*   edges  = (const int*)d_in[1];
    const float* ew     = (const float*)d_in[2];
    const float* pre_g  = (const float*)d_in[3];
    const float* pre_be = (const float*)d_in[4];
    const float* pre_m  = (const float*)d_in[5];
    const float* pre_v  = (const float*)d_in[6];
    const float* pre_w  = (const float*)d_in[7];
    const float* pre_b  = (const float*)d_in[8];
    const float* upd_g  = (const float*)d_in[9];
    const float* upd_be = (const float*)d_in[10];
    const float* upd_m  = (const float*)d_in[11];
    const float* upd_v  = (const float*)d_in[12];
    const float* upd_w  = (const float*)d_in[13];
    const float* upd_b  = (const float*)d_in[14];
    float* out = (float*)d_out;

    const int nNodes = in_sizes[0] / F;
    const int nEdges = in_sizes[2];
    const int nChunks = (nNodes + 1023) / 1024;
    const int histBlocks = 1024;
    const int gB = (nNodes + 63) / 64;
    const int fillBlocks = 1024;

    // ws layout (16B aligned blocks)
    char* p = (char*)d_ws;
    int*      counts    = (int*)p;       p += (size_t)nNodes * 4;
    int*      offsets   = (int*)p;       p += (size_t)(nNodes + 4) * 4;
    int*      cursor    = (int*)p;       p += (size_t)nNodes * 4;
    int*      blocksums = (int*)p;       p += 1024 * 4;
    int2*     csr       = (int2*)p;      p += (size_t)nEdges * 8;
    float*    b1f       = (float*)p;     p += F * 4;
    float*    b2f       = (float*)p;     p += F * 4;
    ushort_t* W1T       = (ushort_t*)p;  p += F * F * 2;
    ushort_t* W2T       = (ushort_t*)p;  p += TWO_F * F * 2;
    uchar_t*  G8        = (uchar_t*)p;

    hipMemsetAsync(counts, 0, (size_t)nNodes * 4, stream);

    prep<<<129 + histBlocks, 256, 0, stream>>>(
        pre_w, pre_b, pre_g, pre_be, pre_m, pre_v,
        upd_w, upd_b, upd_g, upd_be, upd_m, upd_v,
        W1T, W2T, b1f, b2f, edges, counts, nEdges, histBlocks);

    scan_pass1<<<nChunks, 1024, 0, stream>>>(counts, offsets, blocksums, nNodes);
    scan_pass3<<<nChunks, 1024, 0, stream>>>(counts, offsets, blocksums, cursor, nNodes);

    gemm1_fill<<<gB + fillBlocks, 256, 0, stream>>>(
        nodes, W1T, b1f, G8, nNodes, edges, ew, cursor, csr, nEdges, gB, fillBlocks);

    node_fused<<<(nNodes + 31) / 32, 256, 0, stream>>>(
        nodes, G8, offsets, csr, W2T, b2f, out, nNodes);
}

// Round 3
// 297.744 us; speedup vs baseline: 1.2038x; 1.0108x over previous
//
#include <hip/hip_runtime.h>
#include <math.h>

#define F 128
#define TWO_F 256
#define BN_EPS 1e-5f
#define PAD_A 136    // 128+8 bf16 row stride (gemm1 tile)
#define PAD_A2 264   // 256+8 bf16 row stride (gemm2 tile)

typedef unsigned short ushort_t;
typedef unsigned char uchar_t;
typedef __attribute__((ext_vector_type(8))) short bfrag;   // 8 bf16
typedef __attribute__((ext_vector_type(4))) float ffrag;   // 4 fp32
typedef __attribute__((ext_vector_type(2))) float floatx2;

__device__ __forceinline__ float gelu_exact(float x) {
    return 0.5f * x * (1.0f + erff(x * 0.70710678118654752f));
}
__device__ __forceinline__ ushort_t f2bf(float x) {
    unsigned int u = __float_as_uint(x);
    u = (u + 0x7FFFu + ((u >> 16) & 1u)) >> 16;
    return (ushort_t)u;
}
__device__ __forceinline__ unsigned int pk2(float a, float b) {
    return (unsigned int)f2bf(a) | ((unsigned int)f2bf(b) << 16);
}

__device__ __forceinline__ void fma4_fp8(float* acc, unsigned int d, float w) {
    floatx2 lo = __builtin_amdgcn_cvt_pk_f32_fp8(d, false);
    floatx2 hi = __builtin_amdgcn_cvt_pk_f32_fp8(d, true);
    acc[0] = fmaf(w, lo.x, acc[0]);
    acc[1] = fmaf(w, lo.y, acc[1]);
    acc[2] = fmaf(w, hi.x, acc[2]);
    acc[3] = fmaf(w, hi.y, acc[3]);
}
__device__ __forceinline__ void fma16_fp8(float* acc, uint4 a, float w) {
    fma4_fp8(acc + 0,  a.x, w); fma4_fp8(acc + 4,  a.y, w);
    fma4_fp8(acc + 8,  a.z, w); fma4_fp8(acc + 12, a.w, w);
}

// ---------------- prep: param fold (blocks 0..128) + degree histogram (blocks 129+) ----------------
__global__ __launch_bounds__(256) void prep(
    const float* __restrict__ pre_w, const float* __restrict__ pre_b,
    const float* __restrict__ g1, const float* __restrict__ be1,
    const float* __restrict__ m1, const float* __restrict__ v1,
    const float* __restrict__ upd_w, const float* __restrict__ upd_b,
    const float* __restrict__ g2, const float* __restrict__ be2,
    const float* __restrict__ m2, const float* __restrict__ v2,
    ushort_t* __restrict__ W1T, ushort_t* __restrict__ W2T,
    float* __restrict__ b1f, float* __restrict__ b2f,
    const int* __restrict__ edges, int* __restrict__ counts, int nEdges, int histBlocks) {
    const int t = threadIdx.x;
    if (blockIdx.x == 0) {
        __shared__ float t1[F], t2[TWO_F];
        if (t < F) {
            float s = g1[t] * rsqrtf(v1[t] + BN_EPS);
            t1[t] = be1[t] - m1[t] * s;
        }
        {
            float s = g2[t] * rsqrtf(v2[t] + BN_EPS);
            t2[t] = be2[t] - m2[t] * s;
        }
        __syncthreads();
        if (t < F) {
            float acc = pre_b[t];
            #pragma unroll 4
            for (int k = 0; k < F; ++k) acc = fmaf(t1[k], pre_w[k * F + t], acc);
            b1f[t] = acc;
        } else {
            int j = t - F;
            float acc = upd_b[j];
            #pragma unroll 4
            for (int k = 0; k < TWO_F; ++k) acc = fmaf(t2[k], upd_w[k * F + j], acc);
            b2f[j] = acc;
        }
    } else if (blockIdx.x <= 128) {
        int idx = (blockIdx.x - 1) * 256 + t;
        if (idx < F * F) {
            int k = idx & (F - 1), n = idx >> 7;
            float s = g1[k] * rsqrtf(v1[k] + BN_EPS);
            W1T[idx] = f2bf(s * pre_w[k * F + n]);
        }
        {
            int k = idx & (TWO_F - 1), n = idx >> 8;
            float s = g2[k] * rsqrtf(v2[k] + BN_EPS);
            W2T[idx] = f2bf(s * upd_w[k * F + n]);
        }
    } else {
        int b = blockIdx.x - 129;
        for (int i = b * 256 + t; i < nEdges; i += histBlocks * 256)
            atomicAdd(&counts[edges[i]], 1);
    }
}

// ---------------- CSR scans ----------------
__global__ __launch_bounds__(1024) void scan_pass1(const int* __restrict__ counts,
                                                   int* __restrict__ offsets,
                                                   int* __restrict__ blocksums, int n) {
    __shared__ int sb[1024];
    const int t = threadIdx.x;
    int idx = blockIdx.x * 1024 + t;
    int v = (idx < n) ? counts[idx] : 0;
    sb[t] = v;
    __syncthreads();
    for (int off = 1; off < 1024; off <<= 1) {
        int x = (t >= off) ? sb[t - off] : 0;
        __syncthreads();
        sb[t] += x;
        __syncthreads();
    }
    if (idx < n) offsets[idx + 1] = sb[t];
    if (t == 1023) blocksums[blockIdx.x] = sb[t];
}

__global__ __launch_bounds__(1024) void scan_pass3(const int* __restrict__ counts,
                                                   int* __restrict__ offsets,
                                                   const int* __restrict__ blocksums,
                                                   int* __restrict__ cursor, int n) {
    __shared__ int sb[1024];
    const int t = threadIdx.x;
    sb[t] = (t < blockIdx.x) ? blocksums[t] : 0;
    __syncthreads();
    #pragma unroll
    for (int off = 512; off > 0; off >>= 1) {
        if (t < off) sb[t] += sb[t + off];
        __syncthreads();
    }
    int base = sb[0];
    int idx = blockIdx.x * 1024 + t;
    if (idx < n) {
        int incl = offsets[idx + 1] + base;
        offsets[idx + 1] = incl;
        cursor[idx] = incl - counts[idx];
    }
    if (blockIdx.x == 0 && t == 0) offsets[0] = 0;
}

// ---------------- gemm1 (blocks 0..gB-1) + fill_csr (blocks gB+) ----------------
__global__ __launch_bounds__(256) void gemm1_fill(
    const float* __restrict__ nodes, const ushort_t* __restrict__ W1T,
    const float* __restrict__ b1f, uchar_t* __restrict__ G8, int nNodes,
    const int* __restrict__ edges, const float* __restrict__ ew,
    int* __restrict__ cursor, int2* __restrict__ csr, int nEdges,
    int gB, int fillBlocks) {
    __shared__ ushort_t As[64 * PAD_A];
    __shared__ float bs[F];
    const int t = threadIdx.x;

    if (blockIdx.x >= gB) {   // fill_csr part
        int b = blockIdx.x - gB;
        for (int e = b * 256 + t; e < nEdges; e += fillBlocks * 256) {
            int dst = edges[e];
            int pos = atomicAdd(&cursor[dst], 1);
            csr[pos] = make_int2(edges[nEdges + e], __float_as_int(ew[e]));
        }
        return;
    }

    const int base = blockIdx.x * 64;
    {
        int r = t >> 2, q = t & 3;
        int n = base + r;
        int sn = (n < nNodes) ? n : 0;
        const float4* src = reinterpret_cast<const float4*>(nodes + (size_t)sn * F + q * 32);
        uint4 pv[4];
        #pragma unroll
        for (int i = 0; i < 4; ++i) {
            float4 a = src[2 * i], b = src[2 * i + 1];
            pv[i].x = pk2(a.x, a.y); pv[i].y = pk2(a.z, a.w);
            pv[i].z = pk2(b.x, b.y); pv[i].w = pk2(b.z, b.w);
        }
        uint4* dst = reinterpret_cast<uint4*>(As + r * PAD_A + q * 32);
        #pragma unroll
        for (int i = 0; i < 4; ++i) dst[i] = pv[i];
    }
    if (t < F) bs[t] = b1f[t];
    __syncthreads();

    const int lane = t & 63, w = t >> 6;
    const int m = lane & 15, quad = lane >> 4;

    ffrag acc[8];
    #pragma unroll
    for (int c = 0; c < 8; ++c) acc[c] = (ffrag){0.f, 0.f, 0.f, 0.f};

    #pragma unroll
    for (int kk = 0; kk < 4; ++kk) {
        int k0 = kk * 32 + quad * 8;
        bfrag a = *reinterpret_cast<const bfrag*>(As + (w * 16 + m) * PAD_A + k0);
        #pragma unroll
        for (int c = 0; c < 8; ++c) {
            bfrag b = *reinterpret_cast<const bfrag*>(W1T + (size_t)(c * 16 + m) * F + k0);
            acc[c] = __builtin_amdgcn_mfma_f32_16x16x32_bf16(a, b, acc[c], 0, 0, 0);
        }
    }

    #pragma unroll
    for (int c = 0; c < 8; ++c) {
        int feat = c * 16 + m;
        float bj = bs[feat];
        #pragma unroll
        for (int i = 0; i < 4; ++i) {
            int n = base + w * 16 + quad * 4 + i;
            if (n < nNodes) {
                float v = gelu_exact(acc[c][i] + bj);
                int pkd = __builtin_amdgcn_cvt_pk_fp8_f32(v, v, 0, false);
                G8[(size_t)n * F + feat] = (uchar_t)(pkd & 0xFF);
            }
        }
    }
}

// ---------------- gather_agg: pure aggregation, no LDS, no barriers ----------------
// 8 threads/node, 16 fp8 feats each, 8-deep batched independent loads.
// Writes bf16 agg rows (same pk2(acc*inv) math as the old fused path).
__global__ __launch_bounds__(256) void gather_agg(
    const uchar_t* __restrict__ G8, const int* __restrict__ offsets,
    const int2* __restrict__ csr, ushort_t* __restrict__ agg, int nNodes) {
    const int t = threadIdx.x;
    const int gid = blockIdx.x * 32 + (t >> 3);
    const int q = t & 7;
    if (gid >= nNodes) return;
    const int s = offsets[gid], e = offsets[gid + 1];

    float acc[16];
    #pragma unroll
    for (int j = 0; j < 16; ++j) acc[j] = 0.f;

    int i = s;
    while (i < e) {
        int c = e - i;
        c = (c > 8) ? 8 : c;
        uint4 av[8];
        float wv[8];
        #pragma unroll
        for (int j = 0; j < 8; ++j) {
            if (j < c) {
                int2 m = csr[i + j];
                wv[j] = __int_as_float(m.y);
                av[j] = *reinterpret_cast<const uint4*>(
                    G8 + (size_t)(unsigned int)m.x * F + q * 16);
            }
        }
        #pragma unroll
        for (int j = 0; j < 8; ++j)
            if (j < c) fma16_fp8(acc, av[j], wv[j]);
        i += c;
    }

    const int deg = e - s;
    const float inv = (deg > 0) ? 1.0f / ((float)deg * (float)F) : 0.f;  // counter = deg*F quirk
    uint4 pv0, pv1;
    pv0.x = pk2(acc[0] * inv, acc[1] * inv);  pv0.y = pk2(acc[2] * inv, acc[3] * inv);
    pv0.z = pk2(acc[4] * inv, acc[5] * inv);  pv0.w = pk2(acc[6] * inv, acc[7] * inv);
    pv1.x = pk2(acc[8] * inv, acc[9] * inv);  pv1.y = pk2(acc[10] * inv, acc[11] * inv);
    pv1.z = pk2(acc[12] * inv, acc[13] * inv); pv1.w = pk2(acc[14] * inv, acc[15] * inv);
    uint4* d = reinterpret_cast<uint4*>(agg + (size_t)gid * F + q * 16);
    d[0] = pv0; d[1] = pv1;
}

// ---------------- gemm2: [nodes fp32 | agg bf16] x W2T -> gelu -> out ----------------
// 64 rows/block, K=256. 4 waves = 2 row-pairs x 2 col-groups, register-blocked
// rows (2 A-frags share each B-frag) to halve W2T L2 traffic.
__global__ __launch_bounds__(256) void gemm2(
    const float* __restrict__ nodes, const ushort_t* __restrict__ agg,
    const ushort_t* __restrict__ W2T, const float* __restrict__ b2f,
    float* __restrict__ out, int nNodes) {
    __shared__ ushort_t As[64 * PAD_A2];   // 33.8 KB
    __shared__ float bs[F];
    const int t = threadIdx.x;
    const int base = blockIdx.x * 64;

    {
        int r = t >> 2, q = t & 3;
        int n = base + r;
        int sn = (n < nNodes) ? n : 0;
        // nodes half (fp32 -> bf16 pack)
        const float4* src = reinterpret_cast<const float4*>(nodes + (size_t)sn * F + q * 32);
        uint4 pv[4];
        #pragma unroll
        for (int i = 0; i < 4; ++i) {
            float4 a = src[2 * i], b = src[2 * i + 1];
            pv[i].x = pk2(a.x, a.y); pv[i].y = pk2(a.z, a.w);
            pv[i].z = pk2(b.x, b.y); pv[i].w = pk2(b.z, b.w);
        }
        uint4* dst = reinterpret_cast<uint4*>(As + r * PAD_A2 + q * 32);
        #pragma unroll
        for (int i = 0; i < 4; ++i) dst[i] = pv[i];
        // agg half (bf16 copy)
        const uint4* src2 = reinterpret_cast<const uint4*>(agg + (size_t)sn * F) + q * 4;
        uint4* dst2 = reinterpret_cast<uint4*>(As + r * PAD_A2 + F + q * 32);
        #pragma unroll
        for (int i = 0; i < 4; ++i) dst2[i] = src2[i];
    }
    if (t < F) bs[t] = b2f[t];
    __syncthreads();

    const int lane = t & 63, w = t >> 6;
    const int m = lane & 15, quad = lane >> 4;
    const int rg = w & 1, cg = w >> 1;   // rows rg*32..rg*32+31, feats cg*64..cg*64+63

    ffrag acc0[4], acc1[4];
    #pragma unroll
    for (int c = 0; c < 4; ++c) {
        acc0[c] = (ffrag){0.f, 0.f, 0.f, 0.f};
        acc1[c] = (ffrag){0.f, 0.f, 0.f, 0.f};
    }

    #pragma unroll
    for (int kk = 0; kk < 8; ++kk) {
        int k0 = kk * 32 + quad * 8;
        bfrag a0 = *reinterpret_cast<const bfrag*>(As + (rg * 32 + m) * PAD_A2 + k0);
        bfrag a1 = *reinterpret_cast<const bfrag*>(As + (rg * 32 + 16 + m) * PAD_A2 + k0);
        #pragma unroll
        for (int c = 0; c < 4; ++c) {
            int feat = cg * 64 + c * 16 + m;
            bfrag b = *reinterpret_cast<const bfrag*>(W2T + (size_t)feat * TWO_F + k0);
            acc0[c] = __builtin_amdgcn_mfma_f32_16x16x32_bf16(a0, b, acc0[c], 0, 0, 0);
            acc1[c] = __builtin_amdgcn_mfma_f32_16x16x32_bf16(a1, b, acc1[c], 0, 0, 0);
        }
    }

    #pragma unroll
    for (int c = 0; c < 4; ++c) {
        int feat = cg * 64 + c * 16 + m;
        float bj = bs[feat];
        #pragma unroll
        for (int i = 0; i < 4; ++i) {
            int n0 = base + rg * 32 + quad * 4 + i;
            if (n0 < nNodes) out[(size_t)n0 * F + feat] = gelu_exact(acc0[c][i] + bj);
            int n1 = n0 + 16;
            if (n1 < nNodes) out[(size_t)n1 * F + feat] = gelu_exact(acc1[c][i] + bj);
        }
    }
}

extern "C" void kernel_launch(void* const* d_in, const int* in_sizes, int n_in,
                              void* d_out, int out_size, void* d_ws, size_t ws_size,
                              hipStream_t stream) {
    const float* nodes  = (const float*)d_in[0];
    const int*   edges  = (const int*)d_in[1];
    const float* ew     = (const float*)d_in[2];
    const float* pre_g  = (const float*)d_in[3];
    const float* pre_be = (const float*)d_in[4];
    const float* pre_m  = (const float*)d_in[5];
    const float* pre_v  = (const float*)d_in[6];
    const float* pre_w  = (const float*)d_in[7];
    const float* pre_b  = (const float*)d_in[8];
    const float* upd_g  = (const float*)d_in[9];
    const float* upd_be = (const float*)d_in[10];
    const float* upd_m  = (const float*)d_in[11];
    const float* upd_v  = (const float*)d_in[12];
    const float* upd_w  = (const float*)d_in[13];
    const float* upd_b  = (const float*)d_in[14];
    float* out = (float*)d_out;

    const int nNodes = in_sizes[0] / F;
    const int nEdges = in_sizes[2];
    const int nChunks = (nNodes + 1023) / 1024;
    const int histBlocks = 1024;
    const int gB = (nNodes + 63) / 64;
    const int fillBlocks = 1024;

    // ws layout (16B aligned blocks)
    char* p = (char*)d_ws;
    int*      counts    = (int*)p;       p += (size_t)nNodes * 4;
    int*      offsets   = (int*)p;       p += (size_t)(nNodes + 4) * 4;
    int*      cursor    = (int*)p;       p += (size_t)nNodes * 4;
    int*      blocksums = (int*)p;       p += 1024 * 4;
    int2*     csr       = (int2*)p;      p += (size_t)nEdges * 8;
    float*    b1f       = (float*)p;     p += F * 4;
    float*    b2f       = (float*)p;     p += F * 4;
    ushort_t* W1T       = (ushort_t*)p;  p += F * F * 2;
    ushort_t* W2T       = (ushort_t*)p;  p += TWO_F * F * 2;
    uchar_t*  G8        = (uchar_t*)p;   p += (size_t)nNodes * F;
    ushort_t* agg       = (ushort_t*)p;  // nNodes * F bf16

    hipMemsetAsync(counts, 0, (size_t)nNodes * 4, stream);

    prep<<<129 + histBlocks, 256, 0, stream>>>(
        pre_w, pre_b, pre_g, pre_be, pre_m, pre_v,
        upd_w, upd_b, upd_g, upd_be, upd_m, upd_v,
        W1T, W2T, b1f, b2f, edges, counts, nEdges, histBlocks);

    scan_pass1<<<nChunks, 1024, 0, stream>>>(counts, offsets, blocksums, nNodes);
    scan_pass3<<<nChunks, 1024, 0, stream>>>(counts, offsets, blocksums, cursor, nNodes);

    gemm1_fill<<<gB + fillBlocks, 256, 0, stream>>>(
        nodes, W1T, b1f, G8, nNodes, edges, ew, cursor, csr, nEdges, gB, fillBlocks);

    gather_agg<<<(nNodes + 31) / 32, 256, 0, stream>>>(
        G8, offsets, csr, agg, nNodes);

    gemm2<<<(nNodes + 63) / 64, 256, 0, stream>>>(
        nodes, agg, W2T, b2f, out, nNodes);
}

// Round 4
// 267.782 us; speedup vs baseline: 1.3385x; 1.1119x over previous
//
#include <hip/hip_runtime.h>
#include <math.h>

#define F 128
#define TWO_F 256
#define BN_EPS 1e-5f
#define PAD_W1 136   // bf16 row stride for W1T LDS (128+8)
#define PAD_W2 264   // bf16 row stride for W2T LDS (256+8)

typedef unsigned short ushort_t;
typedef unsigned char uchar_t;
typedef __attribute__((ext_vector_type(8))) short bfrag;   // 8 bf16
typedef __attribute__((ext_vector_type(4))) float ffrag;   // 4 fp32
typedef __attribute__((ext_vector_type(2))) float floatx2;

__device__ __forceinline__ float gelu_exact(float x) {
    return 0.5f * x * (1.0f + erff(x * 0.70710678118654752f));
}
__device__ __forceinline__ ushort_t f2bf(float x) {
    unsigned int u = __float_as_uint(x);
    u = (u + 0x7FFFu + ((u >> 16) & 1u)) >> 16;
    return (ushort_t)u;
}
__device__ __forceinline__ unsigned int pk2(float a, float b) {
    return (unsigned int)f2bf(a) | ((unsigned int)f2bf(b) << 16);
}

__device__ __forceinline__ void fma4_fp8(float* acc, unsigned int d, float w) {
    floatx2 lo = __builtin_amdgcn_cvt_pk_f32_fp8(d, false);
    floatx2 hi = __builtin_amdgcn_cvt_pk_f32_fp8(d, true);
    acc[0] = fmaf(w, lo.x, acc[0]);
    acc[1] = fmaf(w, lo.y, acc[1]);
    acc[2] = fmaf(w, hi.x, acc[2]);
    acc[3] = fmaf(w, hi.y, acc[3]);
}
__device__ __forceinline__ void fma16_fp8(float* acc, uint4 a, float w) {
    fma4_fp8(acc + 0,  a.x, w); fma4_fp8(acc + 4,  a.y, w);
    fma4_fp8(acc + 8,  a.z, w); fma4_fp8(acc + 12, a.w, w);
}

// ---------------- prep: param fold (0..128) + nodes->bf16 convert + histogram w/ rank ----------------
__global__ __launch_bounds__(256) void prep(
    const float* __restrict__ pre_w, const float* __restrict__ pre_b,
    const float* __restrict__ g1, const float* __restrict__ be1,
    const float* __restrict__ m1, const float* __restrict__ v1,
    const float* __restrict__ upd_w, const float* __restrict__ upd_b,
    const float* __restrict__ g2, const float* __restrict__ be2,
    const float* __restrict__ m2, const float* __restrict__ v2,
    ushort_t* __restrict__ W1T, ushort_t* __restrict__ W2T,
    float* __restrict__ b1f, float* __restrict__ b2f,
    const float* __restrict__ nodes, ushort_t* __restrict__ NB, int convB, int nNodes,
    const int* __restrict__ edges, int* __restrict__ counts, int* __restrict__ rankb,
    int nEdges, int histBlocks) {
    const int t = threadIdx.x;
    if (blockIdx.x == 0) {
        __shared__ float t1[F], t2[TWO_F];
        if (t < F) {
            float s = g1[t] * rsqrtf(v1[t] + BN_EPS);
            t1[t] = be1[t] - m1[t] * s;
        }
        {
            float s = g2[t] * rsqrtf(v2[t] + BN_EPS);
            t2[t] = be2[t] - m2[t] * s;
        }
        __syncthreads();
        if (t < F) {
            float acc = pre_b[t];
            #pragma unroll 4
            for (int k = 0; k < F; ++k) acc = fmaf(t1[k], pre_w[k * F + t], acc);
            b1f[t] = acc;
        } else {
            int j = t - F;
            float acc = upd_b[j];
            #pragma unroll 4
            for (int k = 0; k < TWO_F; ++k) acc = fmaf(t2[k], upd_w[k * F + j], acc);
            b2f[j] = acc;
        }
    } else if (blockIdx.x <= 128) {
        int idx = (blockIdx.x - 1) * 256 + t;
        if (idx < F * F) {
            int k = idx & (F - 1), n = idx >> 7;
            float s = g1[k] * rsqrtf(v1[k] + BN_EPS);
            W1T[idx] = f2bf(s * pre_w[k * F + n]);
        }
        {
            int k = idx & (TWO_F - 1), n = idx >> 8;
            float s = g2[k] * rsqrtf(v2[k] + BN_EPS);
            W2T[idx] = f2bf(s * upd_w[k * F + n]);
        }
    } else if (blockIdx.x <= 128 + convB) {
        // nodes fp32 -> bf16, 16 elems/thread
        int cb = blockIdx.x - 129;
        long long idx = (long long)cb * 4096 + t * 16;
        if (idx < (long long)nNodes * F) {
            const float4* s = reinterpret_cast<const float4*>(nodes + idx);
            float4 f0 = s[0], f1 = s[1], f2 = s[2], f3 = s[3];
            uint4 o0, o1;
            o0.x = pk2(f0.x, f0.y); o0.y = pk2(f0.z, f0.w);
            o0.z = pk2(f1.x, f1.y); o0.w = pk2(f1.z, f1.w);
            o1.x = pk2(f2.x, f2.y); o1.y = pk2(f2.z, f2.w);
            o1.z = pk2(f3.x, f3.y); o1.w = pk2(f3.z, f3.w);
            uint4* d = reinterpret_cast<uint4*>(NB + idx);
            d[0] = o0; d[1] = o1;
        }
    } else {
        int b = blockIdx.x - 129 - convB;
        for (int i = b * 256 + t; i < nEdges; i += histBlocks * 256) {
            int rk = atomicAdd(&counts[edges[i]], 1);
            rankb[i] = rk;
        }
    }
}

// ---------------- CSR scans ----------------
__global__ __launch_bounds__(1024) void scan_pass1(const int* __restrict__ counts,
                                                   int* __restrict__ offsets,
                                                   int* __restrict__ blocksums, int n) {
    __shared__ int sb[1024];
    const int t = threadIdx.x;
    int idx = blockIdx.x * 1024 + t;
    int v = (idx < n) ? counts[idx] : 0;
    sb[t] = v;
    __syncthreads();
    for (int off = 1; off < 1024; off <<= 1) {
        int x = (t >= off) ? sb[t - off] : 0;
        __syncthreads();
        sb[t] += x;
        __syncthreads();
    }
    if (idx < n) offsets[idx + 1] = sb[t];
    if (t == 1023) blocksums[blockIdx.x] = sb[t];
}

__global__ __launch_bounds__(1024) void scan_pass3(const int* __restrict__ counts,
                                                   int* __restrict__ offsets,
                                                   const int* __restrict__ blocksums,
                                                   int* __restrict__ cursor, int n) {
    __shared__ int sb[1024];
    const int t = threadIdx.x;
    sb[t] = (t < blockIdx.x) ? blocksums[t] : 0;
    __syncthreads();
    #pragma unroll
    for (int off = 512; off > 0; off >>= 1) {
        if (t < off) sb[t] += sb[t + off];
        __syncthreads();
    }
    int base = sb[0];
    int idx = blockIdx.x * 1024 + t;
    if (idx < n) {
        int incl = offsets[idx + 1] + base;
        offsets[idx + 1] = incl;
        cursor[idx] = incl - counts[idx];
    }
    if (blockIdx.x == 0 && t == 0) offsets[0] = 0;
}

// ---------------- gemm1 (persistent, W1T in LDS, barrier-free K-loop) + fill (atomic-free) ----------------
__global__ __launch_bounds__(256) void gemm1_fill(
    const ushort_t* __restrict__ NB, const ushort_t* __restrict__ W1T,
    const float* __restrict__ b1f, uchar_t* __restrict__ G8, int nNodes,
    const int* __restrict__ edges, const float* __restrict__ ew,
    const int* __restrict__ offsets, const int* __restrict__ rankb,
    int2* __restrict__ csr, int nEdges,
    int gemmBlocks, int fillBlocks, int nTiles) {
    __shared__ ushort_t Wl[F * PAD_W1];    // 34.8 KB
    __shared__ float bsm[F];
    __shared__ uchar_t bounce[4][16 * F];  // 8 KB, one 2KB strip per wave
    const int t = threadIdx.x;

    if (blockIdx.x >= gemmBlocks) {   // fill part: no atomics, pure scatter
        int b = blockIdx.x - gemmBlocks;
        for (int e = b * 256 + t; e < nEdges; e += fillBlocks * 256) {
            int dst = edges[e];
            int pos = offsets[dst] + rankb[e];
            csr[pos] = make_int2(edges[nEdges + e], __float_as_int(ew[e]));
        }
        return;
    }

    // stage W1T -> LDS (padded), once per persistent block
    for (int j = t; j < 2048; j += 256) {
        int feat = j >> 4, kc = j & 15;
        *reinterpret_cast<uint4*>(Wl + feat * PAD_W1 + kc * 8) =
            reinterpret_cast<const uint4*>(W1T)[j];
    }
    if (t < F) bsm[t] = b1f[t];
    __syncthreads();

    const int lane = t & 63, w = t >> 6;
    const int m = lane & 15, quad = lane >> 4;
    const int rr = lane >> 2, cc = (lane & 3) * 32;   // bounce readback coords

    for (int tile = blockIdx.x; tile < nTiles; tile += gemmBlocks) {
        const int tb = tile * 64;
        int arow = tb + w * 16 + m;
        if (arow >= nNodes) arow = 0;
        const ushort_t* ap = NB + (size_t)arow * F + quad * 8;

        bfrag a[4];
        #pragma unroll
        for (int kk = 0; kk < 4; ++kk)
            a[kk] = *reinterpret_cast<const bfrag*>(ap + kk * 32);

        ffrag acc[8];
        #pragma unroll
        for (int c = 0; c < 8; ++c) acc[c] = (ffrag){0.f, 0.f, 0.f, 0.f};

        #pragma unroll
        for (int kk = 0; kk < 4; ++kk) {
            int k0 = kk * 32 + quad * 8;
            #pragma unroll
            for (int c = 0; c < 8; ++c) {
                bfrag b = *reinterpret_cast<const bfrag*>(Wl + (c * 16 + m) * PAD_W1 + k0);
                acc[c] = __builtin_amdgcn_mfma_f32_16x16x32_bf16(a[kk], b, acc[c], 0, 0, 0);
            }
        }

        // epilogue: gelu -> fp8 byte into per-wave LDS strip (no barrier: wave-private)
        #pragma unroll
        for (int c = 0; c < 8; ++c) {
            float bj = bsm[c * 16 + m];
            #pragma unroll
            for (int i = 0; i < 4; ++i) {
                float v = gelu_exact(acc[c][i] + bj);
                int pkd = __builtin_amdgcn_cvt_pk_fp8_f32(v, v, 0, false);
                bounce[w][(quad * 4 + i) * F + c * 16 + m] = (uchar_t)(pkd & 0xFF);
            }
        }
        // wave-local readback (compiler inserts lgkmcnt wait) + coalesced stores
        uint4 d0 = *reinterpret_cast<const uint4*>(&bounce[w][rr * F + cc]);
        uint4 d1 = *reinterpret_cast<const uint4*>(&bounce[w][rr * F + cc + 16]);
        int gr = tb + w * 16 + rr;
        if (gr < nNodes) {
            *reinterpret_cast<uint4*>(G8 + (size_t)gr * F + cc) = d0;
            *reinterpret_cast<uint4*>(G8 + (size_t)gr * F + cc + 16) = d1;
        }
    }
}

// ---------------- gather_agg: pure aggregation, no LDS, no barriers ----------------
__global__ __launch_bounds__(256) void gather_agg(
    const uchar_t* __restrict__ G8, const int* __restrict__ offsets,
    const int2* __restrict__ csr, ushort_t* __restrict__ agg, int nNodes) {
    const int t = threadIdx.x;
    const int gid = blockIdx.x * 32 + (t >> 3);
    const int q = t & 7;
    if (gid >= nNodes) return;
    const int s = offsets[gid], e = offsets[gid + 1];

    float acc[16];
    #pragma unroll
    for (int j = 0; j < 16; ++j) acc[j] = 0.f;

    int i = s;
    while (i < e) {
        int c = e - i;
        c = (c > 8) ? 8 : c;
        uint4 av[8];
        float wv[8];
        #pragma unroll
        for (int j = 0; j < 8; ++j) {
            if (j < c) {
                int2 m = csr[i + j];
                wv[j] = __int_as_float(m.y);
                av[j] = *reinterpret_cast<const uint4*>(
                    G8 + (size_t)(unsigned int)m.x * F + q * 16);
            }
        }
        #pragma unroll
        for (int j = 0; j < 8; ++j)
            if (j < c) fma16_fp8(acc, av[j], wv[j]);
        i += c;
    }

    const int deg = e - s;
    const float inv = (deg > 0) ? 1.0f / ((float)deg * (float)F) : 0.f;  // counter = deg*F quirk
    uint4 pv0, pv1;
    pv0.x = pk2(acc[0] * inv, acc[1] * inv);  pv0.y = pk2(acc[2] * inv, acc[3] * inv);
    pv0.z = pk2(acc[4] * inv, acc[5] * inv);  pv0.w = pk2(acc[6] * inv, acc[7] * inv);
    pv1.x = pk2(acc[8] * inv, acc[9] * inv);  pv1.y = pk2(acc[10] * inv, acc[11] * inv);
    pv1.z = pk2(acc[12] * inv, acc[13] * inv); pv1.w = pk2(acc[14] * inv, acc[15] * inv);
    uint4* d = reinterpret_cast<uint4*>(agg + (size_t)gid * F + q * 16);
    d[0] = pv0; d[1] = pv1;
}

// ---------------- gemm2: [NB | agg] x W2T -> gelu -> out. W2T in LDS, barrier-free K-loop ----------------
// 512 threads = 8 waves; each wave 32 rows (2 row-frags, B reuse x2); block tile = 256 rows.
__global__ __launch_bounds__(512, 4) void gemm2(
    const ushort_t* __restrict__ NB, const ushort_t* __restrict__ agg,
    const ushort_t* __restrict__ W2T, const float* __restrict__ b2f,
    float* __restrict__ out, int nNodes) {
    __shared__ ushort_t Wl[F * PAD_W2];   // 67.6 KB
    __shared__ float bsm[F];
    const int t = threadIdx.x;

    for (int j = t; j < 4096; j += 512) {
        int feat = j >> 5, kc = j & 31;
        *reinterpret_cast<uint4*>(Wl + feat * PAD_W2 + kc * 8) =
            reinterpret_cast<const uint4*>(W2T)[j];
    }
    if (t < F) bsm[t] = b2f[t];
    __syncthreads();

    const int lane = t & 63, w = t >> 6;
    const int m = lane & 15, quad = lane >> 4;
    const int tb = blockIdx.x * 256;

    int row0 = tb + w * 32 + m;
    int row1 = row0 + 16;
    int r0c = (row0 < nNodes) ? row0 : 0;
    int r1c = (row1 < nNodes) ? row1 : 0;
    const ushort_t* p0n = NB  + (size_t)r0c * F + quad * 8;
    const ushort_t* p1n = NB  + (size_t)r1c * F + quad * 8;
    const ushort_t* p0a = agg + (size_t)r0c * F + quad * 8;
    const ushort_t* p1a = agg + (size_t)r1c * F + quad * 8;

    ffrag acc0[8], acc1[8];
    #pragma unroll
    for (int c = 0; c < 8; ++c) {
        acc0[c] = (ffrag){0.f, 0.f, 0.f, 0.f};
        acc1[c] = (ffrag){0.f, 0.f, 0.f, 0.f};
    }

    #pragma unroll
    for (int kk = 0; kk < 8; ++kk) {
        int k0 = kk * 32 + quad * 8;
        bfrag a0 = (kk < 4)
            ? *reinterpret_cast<const bfrag*>(p0n + kk * 32)
            : *reinterpret_cast<const bfrag*>(p0a + (kk - 4) * 32);
        bfrag a1 = (kk < 4)
            ? *reinterpret_cast<const bfrag*>(p1n + kk * 32)
            : *reinterpret_cast<const bfrag*>(p1a + (kk - 4) * 32);
        #pragma unroll
        for (int c = 0; c < 8; ++c) {
            bfrag b = *reinterpret_cast<const bfrag*>(Wl + (c * 16 + m) * PAD_W2 + k0);
            acc0[c] = __builtin_amdgcn_mfma_f32_16x16x32_bf16(a0, b, acc0[c], 0, 0, 0);
            acc1[c] = __builtin_amdgcn_mfma_f32_16x16x32_bf16(a1, b, acc1[c], 0, 0, 0);
        }
    }

    #pragma unroll
    for (int c = 0; c < 8; ++c) {
        int feat = c * 16 + m;
        float bj = bsm[feat];
        #pragma unroll
        for (int i = 0; i < 4; ++i) {
            int n0 = tb + w * 32 + quad * 4 + i;
            if (n0 < nNodes) out[(size_t)n0 * F + feat] = gelu_exact(acc0[c][i] + bj);
            int n1 = n0 + 16;
            if (n1 < nNodes) out[(size_t)n1 * F + feat] = gelu_exact(acc1[c][i] + bj);
        }
    }
}

extern "C" void kernel_launch(void* const* d_in, const int* in_sizes, int n_in,
                              void* d_out, int out_size, void* d_ws, size_t ws_size,
                              hipStream_t stream) {
    const float* nodes  = (const float*)d_in[0];
    const int*   edges  = (const int*)d_in[1];
    const float* ew     = (const float*)d_in[2];
    const float* pre_g  = (const float*)d_in[3];
    const float* pre_be = (const float*)d_in[4];
    const float* pre_m  = (const float*)d_in[5];
    const float* pre_v  = (const float*)d_in[6];
    const float* pre_w  = (const float*)d_in[7];
    const float* pre_b  = (const float*)d_in[8];
    const float* upd_g  = (const float*)d_in[9];
    const float* upd_be = (const float*)d_in[10];
    const float* upd_m  = (const float*)d_in[11];
    const float* upd_v  = (const float*)d_in[12];
    const float* upd_w  = (const float*)d_in[13];
    const float* upd_b  = (const float*)d_in[14];
    float* out = (float*)d_out;

    const int nNodes = in_sizes[0] / F;
    const int nEdges = in_sizes[2];
    const int nChunks = (nNodes + 1023) / 1024;
    const int histBlocks = 1024;
    const int convB = (int)(((long long)nNodes * F + 4095) / 4096);
    const int gemmBlocks = 768;
    const int fillBlocks = 512;
    const int nTiles = (nNodes + 63) / 64;

    // ws layout (16B aligned blocks)
    char* p = (char*)d_ws;
    int*      counts    = (int*)p;       p += (size_t)nNodes * 4;
    int*      offsets   = (int*)p;       p += (size_t)(nNodes + 4) * 4;
    int*      cursor    = (int*)p;       p += (size_t)nNodes * 4;
    int*      blocksums = (int*)p;       p += 1024 * 4;
    int2*     csr       = (int2*)p;      p += (size_t)nEdges * 8;
    float*    b1f       = (float*)p;     p += F * 4;
    float*    b2f       = (float*)p;     p += F * 4;
    ushort_t* W1T       = (ushort_t*)p;  p += F * F * 2;
    ushort_t* W2T       = (ushort_t*)p;  p += TWO_F * F * 2;
    uchar_t*  G8        = (uchar_t*)p;   p += (size_t)nNodes * F;
    ushort_t* agg       = (ushort_t*)p;  p += (size_t)nNodes * F * 2;
    int*      rankb     = (int*)p;       p += (size_t)nEdges * 4;
    ushort_t* NB        = (ushort_t*)p;  // nNodes * F bf16

    hipMemsetAsync(counts, 0, (size_t)nNodes * 4, stream);

    prep<<<129 + convB + histBlocks, 256, 0, stream>>>(
        pre_w, pre_b, pre_g, pre_be, pre_m, pre_v,
        upd_w, upd_b, upd_g, upd_be, upd_m, upd_v,
        W1T, W2T, b1f, b2f, nodes, NB, convB, nNodes,
        edges, counts, rankb, nEdges, histBlocks);

    scan_pass1<<<nChunks, 1024, 0, stream>>>(counts, offsets, blocksums, nNodes);
    scan_pass3<<<nChunks, 1024, 0, stream>>>(counts, offsets, blocksums, cursor, nNodes);

    gemm1_fill<<<gemmBlocks + fillBlocks, 256, 0, stream>>>(
        NB, W1T, b1f, G8, nNodes, edges, ew, offsets, rankb, csr, nEdges,
        gemmBlocks, fillBlocks, nTiles);

    gather_agg<<<(nNodes + 31) / 32, 256, 0, stream>>>(
        G8, offsets, csr, agg, nNodes);

    gemm2<<<(nNodes + 255) / 256, 512, 0, stream>>>(
        NB, agg, W2T, b2f, out, nNodes);
}

// Round 5
// 254.432 us; speedup vs baseline: 1.4087x; 1.0525x over previous
//
#include <hip/hip_runtime.h>
#include <math.h>

#define F 128
#define TWO_F 256
#define BN_EPS 1e-5f
#define PAD_W1 136   // bf16 row stride for W1T LDS (128+8)
#define PAD_W2 264   // bf16 row stride for W2T LDS (256+8)

typedef unsigned short ushort_t;
typedef unsigned char uchar_t;
typedef __attribute__((ext_vector_type(8))) short bfrag;   // 8 bf16
typedef __attribute__((ext_vector_type(4))) float ffrag;   // 4 fp32
typedef __attribute__((ext_vector_type(2))) float floatx2;

__device__ __forceinline__ float gelu_exact(float x) {
    return 0.5f * x * (1.0f + erff(x * 0.70710678118654752f));
}
__device__ __forceinline__ ushort_t f2bf(float x) {
    unsigned int u = __float_as_uint(x);
    u = (u + 0x7FFFu + ((u >> 16) & 1u)) >> 16;
    return (ushort_t)u;
}
__device__ __forceinline__ unsigned int pk2(float a, float b) {
    return (unsigned int)f2bf(a) | ((unsigned int)f2bf(b) << 16);
}

__device__ __forceinline__ void fma4_fp8(float* acc, unsigned int d, float w) {
    floatx2 lo = __builtin_amdgcn_cvt_pk_f32_fp8(d, false);
    floatx2 hi = __builtin_amdgcn_cvt_pk_f32_fp8(d, true);
    acc[0] = fmaf(w, lo.x, acc[0]);
    acc[1] = fmaf(w, lo.y, acc[1]);
    acc[2] = fmaf(w, hi.x, acc[2]);
    acc[3] = fmaf(w, hi.y, acc[3]);
}
__device__ __forceinline__ void fma16_fp8(float* acc, uint4 a, float w) {
    fma4_fp8(acc + 0,  a.x, w); fma4_fp8(acc + 4,  a.y, w);
    fma4_fp8(acc + 8,  a.z, w); fma4_fp8(acc + 12, a.w, w);
}

// pack 8 fp32 (two float4) -> one bfrag
__device__ __forceinline__ bfrag pack8(float4 f0, float4 f1) {
    bfrag a;
    unsigned int* au = reinterpret_cast<unsigned int*>(&a);
    au[0] = pk2(f0.x, f0.y); au[1] = pk2(f0.z, f0.w);
    au[2] = pk2(f1.x, f1.y); au[3] = pk2(f1.z, f1.w);
    return a;
}

// ---------------- fold: param fold (block 0) + weight scale (blocks 1..128) ----------------
__global__ __launch_bounds__(256) void fold(
    const float* __restrict__ pre_w, const float* __restrict__ pre_b,
    const float* __restrict__ g1, const float* __restrict__ be1,
    const float* __restrict__ m1, const float* __restrict__ v1,
    const float* __restrict__ upd_w, const float* __restrict__ upd_b,
    const float* __restrict__ g2, const float* __restrict__ be2,
    const float* __restrict__ m2, const float* __restrict__ v2,
    ushort_t* __restrict__ W1T, ushort_t* __restrict__ W2T,
    float* __restrict__ b1f, float* __restrict__ b2f) {
    const int t = threadIdx.x;
    if (blockIdx.x == 0) {
        __shared__ float t1[F], t2[TWO_F];
        if (t < F) {
            float s = g1[t] * rsqrtf(v1[t] + BN_EPS);
            t1[t] = be1[t] - m1[t] * s;
        }
        {
            float s = g2[t] * rsqrtf(v2[t] + BN_EPS);
            t2[t] = be2[t] - m2[t] * s;
        }
        __syncthreads();
        if (t < F) {
            float acc = pre_b[t];
            #pragma unroll 16
            for (int k = 0; k < F; ++k) acc = fmaf(t1[k], pre_w[k * F + t], acc);
            b1f[t] = acc;
        } else {
            int j = t - F;
            float acc = upd_b[j];
            #pragma unroll 16
            for (int k = 0; k < TWO_F; ++k) acc = fmaf(t2[k], upd_w[k * F + j], acc);
            b2f[j] = acc;
        }
    } else {
        int idx = (blockIdx.x - 1) * 256 + t;
        if (idx < F * F) {
            int k = idx & (F - 1), n = idx >> 7;
            float s = g1[k] * rsqrtf(v1[k] + BN_EPS);
            W1T[idx] = f2bf(s * pre_w[k * F + n]);
        }
        {
            int k = idx & (TWO_F - 1), n = idx >> 8;
            float s = g2[k] * rsqrtf(v2[k] + BN_EPS);
            W2T[idx] = f2bf(s * upd_w[k * F + n]);
        }
    }
}

// ---------------- hist: degree histogram + per-edge rank (isolated for attribution) ----------------
__global__ __launch_bounds__(256) void hist(
    const int* __restrict__ edges, int* __restrict__ counts,
    int* __restrict__ rankb, int nEdges) {
    const int stride = gridDim.x * 256;
    for (int i = blockIdx.x * 256 + threadIdx.x; i < nEdges; i += stride) {
        int rk = atomicAdd(&counts[edges[i]], 1);
        rankb[i] = rk;
    }
}

// ---------------- CSR scans ----------------
__global__ __launch_bounds__(1024) void scan_pass1(const int* __restrict__ counts,
                                                   int* __restrict__ offsets,
                                                   int* __restrict__ blocksums, int n) {
    __shared__ int sb[1024];
    const int t = threadIdx.x;
    int idx = blockIdx.x * 1024 + t;
    int v = (idx < n) ? counts[idx] : 0;
    sb[t] = v;
    __syncthreads();
    for (int off = 1; off < 1024; off <<= 1) {
        int x = (t >= off) ? sb[t - off] : 0;
        __syncthreads();
        sb[t] += x;
        __syncthreads();
    }
    if (idx < n) offsets[idx + 1] = sb[t];
    if (t == 1023) blocksums[blockIdx.x] = sb[t];
}

__global__ __launch_bounds__(1024) void scan_pass3(const int* __restrict__ counts,
                                                   int* __restrict__ offsets,
                                                   const int* __restrict__ blocksums,
                                                   int* __restrict__ cursor, int n) {
    __shared__ int sb[1024];
    const int t = threadIdx.x;
    sb[t] = (t < blockIdx.x) ? blocksums[t] : 0;
    __syncthreads();
    #pragma unroll
    for (int off = 512; off > 0; off >>= 1) {
        if (t < off) sb[t] += sb[t + off];
        __syncthreads();
    }
    int base = sb[0];
    int idx = blockIdx.x * 1024 + t;
    if (idx < n) {
        int incl = offsets[idx + 1] + base;
        offsets[idx + 1] = incl;
        cursor[idx] = incl - counts[idx];
    }
    if (blockIdx.x == 0 && t == 0) offsets[0] = 0;
}

// ---------------- gemm1 (persistent, W1T in LDS, A fp32->bf16 in-register) + fill (atomic-free) ----------------
__global__ __launch_bounds__(256) void gemm1_fill(
    const float* __restrict__ nodes, const ushort_t* __restrict__ W1T,
    const float* __restrict__ b1f, uchar_t* __restrict__ G8, int nNodes,
    const int* __restrict__ edges, const float* __restrict__ ew,
    const int* __restrict__ offsets, const int* __restrict__ rankb,
    int2* __restrict__ csr, int nEdges,
    int gemmBlocks, int fillBlocks, int nTiles) {
    __shared__ ushort_t Wl[F * PAD_W1];    // 34.8 KB
    __shared__ float bsm[F];
    __shared__ uchar_t bounce[4][16 * F];  // 8 KB, one 2KB strip per wave
    const int t = threadIdx.x;

    if (blockIdx.x >= gemmBlocks) {   // fill part: no atomics, pure scatter
        int b = blockIdx.x - gemmBlocks;
        for (int e = b * 256 + t; e < nEdges; e += fillBlocks * 256) {
            int dst = edges[e];
            int pos = offsets[dst] + rankb[e];
            csr[pos] = make_int2(edges[nEdges + e], __float_as_int(ew[e]));
        }
        return;
    }

    // stage W1T -> LDS (padded), once per persistent block
    for (int j = t; j < 2048; j += 256) {
        int feat = j >> 4, kc = j & 15;
        *reinterpret_cast<uint4*>(Wl + feat * PAD_W1 + kc * 8) =
            reinterpret_cast<const uint4*>(W1T)[j];
    }
    if (t < F) bsm[t] = b1f[t];
    __syncthreads();

    const int lane = t & 63, w = t >> 6;
    const int m = lane & 15, quad = lane >> 4;
    const int rr = lane >> 2, cc = (lane & 3) * 32;   // bounce readback coords

    for (int tile = blockIdx.x; tile < nTiles; tile += gemmBlocks) {
        const int tb = tile * 64;
        int arow = tb + w * 16 + m;
        if (arow >= nNodes) arow = 0;
        const float* ap = nodes + (size_t)arow * F + quad * 8;

        bfrag a[4];
        #pragma unroll
        for (int kk = 0; kk < 4; ++kk) {
            float4 f0 = *reinterpret_cast<const float4*>(ap + kk * 32);
            float4 f1 = *reinterpret_cast<const float4*>(ap + kk * 32 + 4);
            a[kk] = pack8(f0, f1);
        }

        ffrag acc[8];
        #pragma unroll
        for (int c = 0; c < 8; ++c) acc[c] = (ffrag){0.f, 0.f, 0.f, 0.f};

        #pragma unroll
        for (int kk = 0; kk < 4; ++kk) {
            int k0 = kk * 32 + quad * 8;
            #pragma unroll
            for (int c = 0; c < 8; ++c) {
                bfrag b = *reinterpret_cast<const bfrag*>(Wl + (c * 16 + m) * PAD_W1 + k0);
                acc[c] = __builtin_amdgcn_mfma_f32_16x16x32_bf16(a[kk], b, acc[c], 0, 0, 0);
            }
        }

        // epilogue: gelu -> fp8 byte into per-wave LDS strip (no barrier: wave-private)
        #pragma unroll
        for (int c = 0; c < 8; ++c) {
            float bj = bsm[c * 16 + m];
            #pragma unroll
            for (int i = 0; i < 4; ++i) {
                float v = gelu_exact(acc[c][i] + bj);
                int pkd = __builtin_amdgcn_cvt_pk_fp8_f32(v, v, 0, false);
                bounce[w][(quad * 4 + i) * F + c * 16 + m] = (uchar_t)(pkd & 0xFF);
            }
        }
        // wave-local readback (compiler inserts lgkmcnt wait) + coalesced stores
        uint4 d0 = *reinterpret_cast<const uint4*>(&bounce[w][rr * F + cc]);
        uint4 d1 = *reinterpret_cast<const uint4*>(&bounce[w][rr * F + cc + 16]);
        int gr = tb + w * 16 + rr;
        if (gr < nNodes) {
            *reinterpret_cast<uint4*>(G8 + (size_t)gr * F + cc) = d0;
            *reinterpret_cast<uint4*>(G8 + (size_t)gr * F + cc + 16) = d1;
        }
    }
}

// ---------------- gather_agg: pure aggregation, no LDS, no barriers ----------------
__global__ __launch_bounds__(256) void gather_agg(
    const uchar_t* __restrict__ G8, const int* __restrict__ offsets,
    const int2* __restrict__ csr, ushort_t* __restrict__ agg, int nNodes) {
    const int t = threadIdx.x;
    const int gid = blockIdx.x * 32 + (t >> 3);
    const int q = t & 7;
    if (gid >= nNodes) return;
    const int s = offsets[gid], e = offsets[gid + 1];

    float acc[16];
    #pragma unroll
    for (int j = 0; j < 16; ++j) acc[j] = 0.f;

    int i = s;
    while (i < e) {
        int c = e - i;
        c = (c > 8) ? 8 : c;
        uint4 av[8];
        float wv[8];
        #pragma unroll
        for (int j = 0; j < 8; ++j) {
            if (j < c) {
                int2 m = csr[i + j];
                wv[j] = __int_as_float(m.y);
                av[j] = *reinterpret_cast<const uint4*>(
                    G8 + (size_t)(unsigned int)m.x * F + q * 16);
            }
        }
        #pragma unroll
        for (int j = 0; j < 8; ++j)
            if (j < c) fma16_fp8(acc, av[j], wv[j]);
        i += c;
    }

    const int deg = e - s;
    const float inv = (deg > 0) ? 1.0f / ((float)deg * (float)F) : 0.f;  // counter = deg*F quirk
    uint4 pv0, pv1;
    pv0.x = pk2(acc[0] * inv, acc[1] * inv);  pv0.y = pk2(acc[2] * inv, acc[3] * inv);
    pv0.z = pk2(acc[4] * inv, acc[5] * inv);  pv0.w = pk2(acc[6] * inv, acc[7] * inv);
    pv1.x = pk2(acc[8] * inv, acc[9] * inv);  pv1.y = pk2(acc[10] * inv, acc[11] * inv);
    pv1.z = pk2(acc[12] * inv, acc[13] * inv); pv1.w = pk2(acc[14] * inv, acc[15] * inv);
    uint4* d = reinterpret_cast<uint4*>(agg + (size_t)gid * F + q * 16);
    d[0] = pv0; d[1] = pv1;
}

// ---------------- gemm2: [nodes fp32 (packed in-reg) | agg bf16] x W2T -> gelu -> out ----------------
// 512 threads = 8 waves; each wave 32 rows (2 row-frags, B reuse x2); block tile = 256 rows.
__global__ __launch_bounds__(512, 4) void gemm2(
    const float* __restrict__ nodes, const ushort_t* __restrict__ agg,
    const ushort_t* __restrict__ W2T, const float* __restrict__ b2f,
    float* __restrict__ out, int nNodes) {
    __shared__ ushort_t Wl[F * PAD_W2];   // 67.6 KB
    __shared__ float bsm[F];
    const int t = threadIdx.x;

    for (int j = t; j < 4096; j += 512) {
        int feat = j >> 5, kc = j & 31;
        *reinterpret_cast<uint4*>(Wl + feat * PAD_W2 + kc * 8) =
            reinterpret_cast<const uint4*>(W2T)[j];
    }
    if (t < F) bsm[t] = b2f[t];
    __syncthreads();

    const int lane = t & 63, w = t >> 6;
    const int m = lane & 15, quad = lane >> 4;
    const int tb = blockIdx.x * 256;

    int row0 = tb + w * 32 + m;
    int row1 = row0 + 16;
    int r0c = (row0 < nNodes) ? row0 : 0;
    int r1c = (row1 < nNodes) ? row1 : 0;
    const float*    p0n = nodes + (size_t)r0c * F + quad * 8;
    const float*    p1n = nodes + (size_t)r1c * F + quad * 8;
    const ushort_t* p0a = agg   + (size_t)r0c * F + quad * 8;
    const ushort_t* p1a = agg   + (size_t)r1c * F + quad * 8;

    ffrag acc0[8], acc1[8];
    #pragma unroll
    for (int c = 0; c < 8; ++c) {
        acc0[c] = (ffrag){0.f, 0.f, 0.f, 0.f};
        acc1[c] = (ffrag){0.f, 0.f, 0.f, 0.f};
    }

    #pragma unroll
    for (int kk = 0; kk < 8; ++kk) {
        int k0 = kk * 32 + quad * 8;
        bfrag a0, a1;
        if (kk < 4) {
            float4 f0 = *reinterpret_cast<const float4*>(p0n + kk * 32);
            float4 f1 = *reinterpret_cast<const float4*>(p0n + kk * 32 + 4);
            a0 = pack8(f0, f1);
            float4 g0 = *reinterpret_cast<const float4*>(p1n + kk * 32);
            float4 g1 = *reinterpret_cast<const float4*>(p1n + kk * 32 + 4);
            a1 = pack8(g0, g1);
        } else {
            a0 = *reinterpret_cast<const bfrag*>(p0a + (kk - 4) * 32);
            a1 = *reinterpret_cast<const bfrag*>(p1a + (kk - 4) * 32);
        }
        #pragma unroll
        for (int c = 0; c < 8; ++c) {
            bfrag b = *reinterpret_cast<const bfrag*>(Wl + (c * 16 + m) * PAD_W2 + k0);
            acc0[c] = __builtin_amdgcn_mfma_f32_16x16x32_bf16(a0, b, acc0[c], 0, 0, 0);
            acc1[c] = __builtin_amdgcn_mfma_f32_16x16x32_bf16(a1, b, acc1[c], 0, 0, 0);
        }
    }

    #pragma unroll
    for (int c = 0; c < 8; ++c) {
        int feat = c * 16 + m;
        float bj = bsm[feat];
        #pragma unroll
        for (int i = 0; i < 4; ++i) {
            int n0 = tb + w * 32 + quad * 4 + i;
            if (n0 < nNodes) out[(size_t)n0 * F + feat] = gelu_exact(acc0[c][i] + bj);
            int n1 = n0 + 16;
            if (n1 < nNodes) out[(size_t)n1 * F + feat] = gelu_exact(acc1[c][i] + bj);
        }
    }
}

extern "C" void kernel_launch(void* const* d_in, const int* in_sizes, int n_in,
                              void* d_out, int out_size, void* d_ws, size_t ws_size,
                              hipStream_t stream) {
    const float* nodes  = (const float*)d_in[0];
    const int*   edges  = (const int*)d_in[1];
    const float* ew     = (const float*)d_in[2];
    const float* pre_g  = (const float*)d_in[3];
    const float* pre_be = (const float*)d_in[4];
    const float* pre_m  = (const float*)d_in[5];
    const float* pre_v  = (const float*)d_in[6];
    const float* pre_w  = (const float*)d_in[7];
    const float* pre_b  = (const float*)d_in[8];
    const float* upd_g  = (const float*)d_in[9];
    const float* upd_be = (const float*)d_in[10];
    const float* upd_m  = (const float*)d_in[11];
    const float* upd_v  = (const float*)d_in[12];
    const float* upd_w  = (const float*)d_in[13];
    const float* upd_b  = (const float*)d_in[14];
    float* out = (float*)d_out;

    const int nNodes = in_sizes[0] / F;
    const int nEdges = in_sizes[2];
    const int nChunks = (nNodes + 1023) / 1024;
    const int histBlocks = 1024;
    const int gemmBlocks = 768;
    const int fillBlocks = 512;
    const int nTiles = (nNodes + 63) / 64;

    // ws layout (16B aligned blocks)
    char* p = (char*)d_ws;
    int*      counts    = (int*)p;       p += (size_t)nNodes * 4;
    int*      offsets   = (int*)p;       p += (size_t)(nNodes + 4) * 4;
    int*      cursor    = (int*)p;       p += (size_t)nNodes * 4;
    int*      blocksums = (int*)p;       p += 1024 * 4;
    int2*     csr       = (int2*)p;      p += (size_t)nEdges * 8;
    float*    b1f       = (float*)p;     p += F * 4;
    float*    b2f       = (float*)p;     p += F * 4;
    ushort_t* W1T       = (ushort_t*)p;  p += F * F * 2;
    ushort_t* W2T       = (ushort_t*)p;  p += TWO_F * F * 2;
    uchar_t*  G8        = (uchar_t*)p;   p += (size_t)nNodes * F;
    ushort_t* agg       = (ushort_t*)p;  p += (size_t)nNodes * F * 2;
    int*      rankb     = (int*)p;       // nEdges * 4

    hipMemsetAsync(counts, 0, (size_t)nNodes * 4, stream);

    fold<<<129, 256, 0, stream>>>(
        pre_w, pre_b, pre_g, pre_be, pre_m, pre_v,
        upd_w, upd_b, upd_g, upd_be, upd_m, upd_v,
        W1T, W2T, b1f, b2f);

    hist<<<histBlocks, 256, 0, stream>>>(edges, counts, rankb, nEdges);

    scan_pass1<<<nChunks, 1024, 0, stream>>>(counts, offsets, blocksums, nNodes);
    scan_pass3<<<nChunks, 1024, 0, stream>>>(counts, offsets, blocksums, cursor, nNodes);

    gemm1_fill<<<gemmBlocks + fillBlocks, 256, 0, stream>>>(
        nodes, W1T, b1f, G8, nNodes, edges, ew, offsets, rankb, csr, nEdges,
        gemmBlocks, fillBlocks, nTiles);

    gather_agg<<<(nNodes + 31) / 32, 256, 0, stream>>>(
        G8, offsets, csr, agg, nNodes);

    gemm2<<<(nNodes + 255) / 256, 512, 0, stream>>>(
        nodes, agg, W2T, b2f, out, nNodes);
}